// Round 6
// baseline (269.499 us; speedup 1.0000x reference)
//
#include <hip/hip_runtime.h>

// B=2, S=2048, D=1024, H=16, DK=64
// out = attn_mean @ vs @ Wo  (Wv shared across heads => mean_h(attn_h @ vs) = attn_mean @ vs)
// attn_mean[b,s,t] = (1/H) sum_h exp(score)/denom  -- no max-subtraction (scores bounded ~|2.5|)
// qs/ks layout: [b*S+s][h*64+dk]  (concatenated-head GEMM output)
// All LDS tiles are FRAGMENT-MAJOR: 16B-unit index = tile*64 + quad*16 + l15
//   -> reader addr = tilebase + lane*16B, conflict-free for ds_read_b128.
#define B_ 2
#define S_ 2048
#define D_ 1024
#define H_ 16
#define DK_ 64

typedef __bf16 bf8 __attribute__((ext_vector_type(8)));
typedef float f4 __attribute__((ext_vector_type(4)));
typedef unsigned short u16x8 __attribute__((ext_vector_type(8)));

__device__ __forceinline__ unsigned short f2bf_bits(float f) {
  unsigned int u = __float_as_uint(f);
  return (unsigned short)((u + 0x7fffu + ((u >> 16) & 1u)) >> 16);
}

__device__ __forceinline__ bf8 pack_bf8(f4 lo, f4 hi) {
  u16x8 u;
  u[0] = f2bf_bits(lo[0]); u[1] = f2bf_bits(lo[1]);
  u[2] = f2bf_bits(lo[2]); u[3] = f2bf_bits(lo[3]);
  u[4] = f2bf_bits(hi[0]); u[5] = f2bf_bits(hi[1]);
  u[6] = f2bf_bits(hi[2]); u[7] = f2bf_bits(hi[3]);
  union { u16x8 u; bf8 b; } x; x.u = u; return x.b;
}

__device__ __forceinline__ bf8 ldb(const unsigned short* p) {
  return *reinterpret_cast<const bf8*>(p);
}

__device__ __forceinline__ void stage16(const void* g, void* l) {
  __builtin_amdgcn_global_load_lds(
      (const __attribute__((address_space(1))) void*)g,
      (__attribute__((address_space(3))) void*)l, 16, 0, 0);
}

#define MFMA(a, b, c) __builtin_amdgcn_mfma_f32_16x16x32_bf16((a), (b), (c), 0, 0, 0)

// ---- merged prep: cast q,k -> bf16 rows; LDS-tiled transpose-cast weights ----
__global__ void k_prep(const float* __restrict__ q, const float* __restrict__ k,
                       const float* __restrict__ wq, const float* __restrict__ wk,
                       const float* __restrict__ wv, const float* __restrict__ wo,
                       unsigned short* __restrict__ qb, unsigned short* __restrict__ kb,
                       unsigned short* __restrict__ wqt, unsigned short* __restrict__ wkt,
                       unsigned short* __restrict__ wvt, unsigned short* __restrict__ wot) {
  __shared__ float tl[64 * 65];
  int bid = blockIdx.x, tid = threadIdx.x;
  const int rr = tid >> 6, cc = tid & 63;
  if (bid < 4096) {
    int which = bid >> 11;
    long i = ((long)(bid & 2047) * 256 + tid) * 8;
    const float* src = which ? k : q;
    unsigned short* dst = which ? kb : qb;
    f4 lo = *reinterpret_cast<const f4*>(src + i);
    f4 hi = *reinterpret_cast<const f4*>(src + i + 4);
    *reinterpret_cast<bf8*>(dst + i) = pack_bf8(lo, hi);
  } else if (bid < 4352) {
    // Wq/Wk [h][d][n=dk] -> [h][n][d], 64x64 f32 tile via LDS
    int blk = bid - 4096;
    int h = blk >> 4, d0 = (blk & 15) * 64;
    for (int m = 0; m < 2; ++m) {
      const float* src = m ? wk : wq;
      unsigned short* dst = m ? wkt : wqt;
      if (m) __syncthreads();
#pragma unroll
      for (int it = 0; it < 16; ++it) {
        int d = it * 4 + rr;
        tl[cc * 65 + d] = src[(long)h * 65536 + (d0 + d) * 64 + cc];
      }
      __syncthreads();
#pragma unroll
      for (int it = 0; it < 16; ++it) {
        int n = it * 4 + rr;
        dst[(long)h * 65536 + n * 1024 + d0 + cc] = f2bf_bits(tl[n * 65 + cc]);
      }
    }
  } else if (bid < 4368) {
    // Wv [d][n] -> [n][d]
    int d0 = (bid - 4352) * 64;
#pragma unroll
    for (int it = 0; it < 16; ++it) {
      int d = it * 4 + rr;
      tl[cc * 65 + d] = wv[(long)(d0 + d) * 64 + cc];
    }
    __syncthreads();
#pragma unroll
    for (int it = 0; it < 16; ++it) {
      int n = it * 4 + rr;
      wvt[(long)n * 1024 + d0 + cc] = f2bf_bits(tl[n * 65 + cc]);
    }
  } else {
    // Wo [kk][dd] -> [dd][kk]
    int d0 = (bid - 4368) * 64;
#pragma unroll
    for (int it = 0; it < 16; ++it) {
      int kk = it * 4 + rr;
      tl[cc * 65 + kk] = wo[(long)kk * 1024 + d0 + cc];
    }
    __syncthreads();
#pragma unroll
    for (int it = 0; it < 16; ++it) {
      int ddl = it * 4 + rr;
      wot[(long)(d0 + ddl) * 64 + cc] = f2bf_bits(tl[ddl * 65 + cc]);
    }
  }
}

// ---- GEMM: C[4096][1024] = X @ W^T, 128x128 tile, BK=64 (32 MFMA/barrier), frag-major LDS ----
// grid (32 m-tiles, 8 n-tiles, which), block 256 (4 waves 2x2; wave = 64m x 64n, 4x4 MFMA)
__global__ __launch_bounds__(256) void k_gemm_qk(
    const unsigned short* __restrict__ qb, const unsigned short* __restrict__ kb,
    const unsigned short* __restrict__ wqt, const unsigned short* __restrict__ wkt,
    unsigned short* __restrict__ qsb, unsigned short* __restrict__ ksb) {
  __shared__ unsigned short lds[16384];         // A 16 tiles @0, B 16 tiles @8192 (tile=512 shorts)
  const int tid = threadIdx.x, wave = tid >> 6, lane = tid & 63;
  const int l15 = lane & 15, quad = lane >> 4;
  const int m0 = blockIdx.x * 128, n0 = blockIdx.y * 128;
  const int which = blockIdx.z;
  const unsigned short* A = which ? kb : qb;
  const unsigned short* W = which ? wkt : wqt;
  unsigned short* C = which ? ksb : qsb;
  const float scale = which ? 1.0f : 0.18033688011112042f;  // log2(e)/8 folded into qs
  const int wr = wave >> 1, wc = wave & 1;

  f4 acc[4][4];
#pragma unroll
  for (int i = 0; i < 4; ++i)
#pragma unroll
    for (int j = 0; j < 4; ++j) acc[i][j] = f4{0.f, 0.f, 0.f, 0.f};

  for (int k0 = 0; k0 < D_; k0 += 64) {
#pragma unroll
    for (int i = 0; i < 4; ++i) {
      int u = i * 256 + tid;
      int T = u >> 6, rg = T & 7, kh = T >> 3, sl15 = u & 15, squad = (u >> 4) & 3;
      stage16(A + (long)(m0 + rg * 16 + sl15) * D_ + k0 + kh * 32 + squad * 8, lds + u * 8);
      stage16(W + (long)(n0 + rg * 16 + sl15) * D_ + k0 + kh * 32 + squad * 8,
              lds + 8192 + u * 8);
    }
    __syncthreads();
#pragma unroll
    for (int kh = 0; kh < 2; ++kh) {
      bf8 aF[4], bF[4];
#pragma unroll
      for (int mi = 0; mi < 4; ++mi)
        aF[mi] = ldb(lds + (wr * 4 + mi + 8 * kh) * 512 + lane * 8);
#pragma unroll
      for (int ni = 0; ni < 4; ++ni)
        bF[ni] = ldb(lds + 8192 + (wc * 4 + ni + 8 * kh) * 512 + lane * 8);
#pragma unroll
      for (int mi = 0; mi < 4; ++mi)
#pragma unroll
        for (int ni = 0; ni < 4; ++ni)
          acc[mi][ni] = MFMA(aF[mi], bF[ni], acc[mi][ni]);
    }
    __syncthreads();
  }
#pragma unroll
  for (int mi = 0; mi < 4; ++mi)
#pragma unroll
    for (int r = 0; r < 4; ++r) {
      long row = m0 + wr * 64 + mi * 16 + quad * 4 + r;
#pragma unroll
      for (int ni = 0; ni < 4; ++ni)
        C[row * D_ + n0 + wc * 64 + ni * 16 + l15] = f2bf_bits(acc[mi][ni][r] * scale);
    }
}

// ---- V projection split-K x8: pv[kc][row][64] f32, kc chunk = 128 ----
__global__ __launch_bounds__(256) void k_pv(
    const float* __restrict__ v, const unsigned short* __restrict__ wvt,
    float* __restrict__ pv) {
  const int tid = threadIdx.x, wave = tid >> 6, lane = tid & 63;
  const int l15 = lane & 15, quad = lane >> 4;
  const int rg = blockIdx.x, kc = blockIdx.y;
  const int row0 = rg * 64 + wave * 16;
  const float* arow = v + (long)(row0 + l15) * D_ + kc * 128 + quad * 8;
  const unsigned short* wbase = wvt + kc * 128 + quad * 8;
  f4 acc[4];
  for (int i = 0; i < 4; ++i) acc[i] = f4{0.f, 0.f, 0.f, 0.f};
#pragma unroll
  for (int k0 = 0; k0 < 128; k0 += 32) {
    f4 alo = *reinterpret_cast<const f4*>(arow + k0);
    f4 ahi = *reinterpret_cast<const f4*>(arow + k0 + 4);
    bf8 a = pack_bf8(alo, ahi);
#pragma unroll
    for (int i = 0; i < 4; ++i) {
      bf8 bf = ldb(wbase + (long)(i * 16 + l15) * D_ + k0);
      acc[i] = MFMA(a, bf, acc[i]);
    }
  }
#pragma unroll
  for (int i = 0; i < 4; ++i)
#pragma unroll
    for (int r = 0; r < 4; ++r)
      pv[((long)kc * 4096 + row0 + quad * 4 + r) * 64 + i * 16 + l15] = acc[i][r];
}

// reduce 8 k-partials -> vst[b][dk][t] bf16
__global__ void k_vred(const float* __restrict__ pv, unsigned short* __restrict__ vst) {
  int e = blockIdx.x * 256 + threadIdx.x;      // e = (b*64+dk)*2048 + t
  int t = e & 2047, dk = (e >> 11) & 63, b = e >> 17;
  long row = (long)b * S_ + t;
  float s = 0.f;
#pragma unroll
  for (int c = 0; c < 8; ++c) s += pv[((long)c * 4096 + row) * 64 + dk];
  vst[e] = f2bf_bits(s);
}

// ---- pass 1: dsum[thalf][b,h,s] = sum_{t in half} exp2(qs.ks) ----
// grid (16 s-tiles x 2 thalf, H, B), block 256 (4 waves x 32 s-rows); dbuf, 1 barrier/chunk
__global__ __launch_bounds__(256) void k_denom(
    const unsigned short* __restrict__ qsb, const unsigned short* __restrict__ ksb,
    float* __restrict__ dsum) {
  __shared__ unsigned short lds[16384];        // 2 bufs x (128t x 64dk)
  const int tid = threadIdx.x, wave = tid >> 6, lane = tid & 63;
  const int l15 = lane & 15, quad = lane >> 4;
  const int stile = blockIdx.x >> 1, thalf = blockIdx.x & 1;
  const int h = blockIdx.y, b = blockIdx.z;
  const int sw = stile * 128 + wave * 32;

  const unsigned short* qrow0 = qsb + ((long)(b * S_) + sw + l15) * D_ + h * 64 + quad * 8;
  bf8 a0 = ldb(qrow0);
  bf8 a1 = ldb(qrow0 + 32);
  bf8 a2 = ldb(qrow0 + 16 * D_);
  bf8 a3 = ldb(qrow0 + 16 * D_ + 32);

  f4 sum0 = f4{0.f, 0.f, 0.f, 0.f}, sum1 = f4{0.f, 0.f, 0.f, 0.f};

  // staging decode (u = i*256+tid over 1024 16B-units): T=u>>6, rg=T&7, kh=T>>3
  const int sl15 = tid & 15, squad = (tid >> 4) & 3;
  const unsigned short* gk[4];
#pragma unroll
  for (int i = 0; i < 4; ++i) {
    int u = i * 256 + tid;
    int T = u >> 6, rg = T & 7, kh = T >> 3;
    gk[i] = ksb + ((long)(b * S_) + thalf * 1024 + rg * 16 + sl15) * D_ + h * 64 + kh * 32 + squad * 8;
  }
#pragma unroll
  for (int i = 0; i < 4; ++i) stage16(gk[i], lds + (i * 256 + tid) * 8);

  for (int it = 0; it < 8; ++it) {
    __syncthreads();
    if (it < 7) {
      int bufn = (it + 1) & 1;
#pragma unroll
      for (int i = 0; i < 4; ++i)
        stage16(gk[i] + (long)(it + 1) * 128 * D_, lds + bufn * 8192 + (i * 256 + tid) * 8);
    }
    const unsigned short* L = lds + (it & 1) * 8192;
#pragma unroll
    for (int tt = 0; tt < 8; ++tt) {
      bf8 b0 = ldb(L + tt * 512 + lane * 8);
      bf8 b1 = ldb(L + 4096 + tt * 512 + lane * 8);
      f4 d0 = f4{0.f, 0.f, 0.f, 0.f};
      d0 = MFMA(a0, b0, d0);
      d0 = MFMA(a1, b1, d0);
      f4 d1 = f4{0.f, 0.f, 0.f, 0.f};
      d1 = MFMA(a2, b0, d1);
      d1 = MFMA(a3, b1, d1);
#pragma unroll
      for (int r = 0; r < 4; ++r) {
        sum0[r] += __builtin_amdgcn_exp2f(d0[r]);
        sum1[r] += __builtin_amdgcn_exp2f(d1[r]);
      }
    }
  }
#pragma unroll
  for (int m = 1; m < 16; m <<= 1) {
#pragma unroll
    for (int r = 0; r < 4; ++r) {
      sum0[r] += __shfl_xor(sum0[r], m, 64);
      sum1[r] += __shfl_xor(sum1[r], m, 64);
    }
  }
  if (l15 == 0) {
    float* dp = dsum + (long)thalf * 65536 + (long)(b * H_ + h) * S_ + sw + quad * 4;
#pragma unroll
    for (int r = 0; r < 4; ++r) {
      dp[r] = sum0[r];
      dp[16 + r] = sum1[r];
    }
  }
}

// recip[e] = 1/(H*(dsum0+dsum1)), e over B*H*S = 65536
__global__ void k_recip(const float* __restrict__ dsum, float* __restrict__ recip) {
  int e = blockIdx.x * 256 + threadIdx.x;
  recip[e] = 1.0f / (16.0f * (dsum[e] + dsum[e + 65536]));
}

// ---- pass 2: attn_mean[b,s,t] = sum_h recip[b,h,s]*exp2(score) ----
// grid (32 t-chunks of 64, 8 s-tiles of 256, B), block 512 (8 waves x 32 s-rows)
// dbuf 2x8KB LDS, 1 barrier per head, prefetch next head's ks tile
__global__ __launch_bounds__(512) void k_attn(
    const unsigned short* __restrict__ qsb, const unsigned short* __restrict__ ksb,
    const float* __restrict__ recip, float* __restrict__ am) {
  __shared__ unsigned short lds[8192];         // 2 bufs x (64t x 64dk)
  const int tid = threadIdx.x, wave = tid >> 6, lane = tid & 63;
  const int l15 = lane & 15, quad = lane >> 4;
  const int tchunk = blockIdx.x, stile = blockIdx.y, b = blockIdx.z;
  const int sw = stile * 256 + wave * 32;
  const int t0c = tchunk * 64;

  f4 acc0[4], acc1[4];
#pragma unroll
  for (int tt = 0; tt < 4; ++tt) {
    acc0[tt] = f4{0.f, 0.f, 0.f, 0.f};
    acc1[tt] = f4{0.f, 0.f, 0.f, 0.f};
  }

  const unsigned short* qrow0 = qsb + ((long)(b * S_) + sw + l15) * D_ + quad * 8;

  // staging decode (u = tid over 512 16B-units): T=u>>6, rg=T&3, kh=T>>2
  const int sl15 = tid & 15, squad = (tid >> 4) & 3;
  const int srg = (tid >> 6) & 3, skh = tid >> 8;
  const unsigned short* gk =
      ksb + ((long)(b * S_) + t0c + srg * 16 + sl15) * D_ + skh * 32 + squad * 8;

  stage16(gk, lds + tid * 8);
  for (int h = 0; h < H_; ++h) {
    __syncthreads();
    if (h < 15)
      stage16(gk + (h + 1) * 64, lds + ((h + 1) & 1) * 4096 + tid * 8);
    const unsigned short* L = lds + (h & 1) * 4096;
    bf8 a0 = ldb(qrow0 + h * 64);
    bf8 a1 = ldb(qrow0 + h * 64 + 32);
    bf8 a2 = ldb(qrow0 + 16 * D_ + h * 64);
    bf8 a3 = ldb(qrow0 + 16 * D_ + h * 64 + 32);
    const float* rpp = recip + (long)(b * H_ + h) * S_ + sw + quad * 4;
    f4 rp0 = *reinterpret_cast<const f4*>(rpp);
    f4 rp1 = *reinterpret_cast<const f4*>(rpp + 16);
#pragma unroll
    for (int tt = 0; tt < 4; ++tt) {
      bf8 b0 = ldb(L + tt * 512 + lane * 8);
      bf8 b1 = ldb(L + 2048 + tt * 512 + lane * 8);
      f4 d0 = f4{0.f, 0.f, 0.f, 0.f};
      d0 = MFMA(a0, b0, d0);
      d0 = MFMA(a1, b1, d0);
      f4 d1 = f4{0.f, 0.f, 0.f, 0.f};
      d1 = MFMA(a2, b0, d1);
      d1 = MFMA(a3, b1, d1);
#pragma unroll
      for (int r = 0; r < 4; ++r) {
        acc0[tt][r] += rp0[r] * __builtin_amdgcn_exp2f(d0[r]);
        acc1[tt][r] += rp1[r] * __builtin_amdgcn_exp2f(d1[r]);
      }
    }
  }
  float* ob0 = am + ((long)b * S_ + sw + quad * 4) * S_ + t0c + l15;
  float* ob1 = ob0 + 16 * S_;
#pragma unroll
  for (int tt = 0; tt < 4; ++tt)
#pragma unroll
    for (int r = 0; r < 4; ++r) {
      ob0[(long)r * S_ + tt * 16] = acc0[tt][r];
      ob1[(long)r * S_ + tt * 16] = acc1[tt][r];
    }
}

// ---- head split-K x8: ph[kc][row][64] f32 = am-chunk @ vs-chunk, kc chunk = 256 t ----
__global__ __launch_bounds__(256) void k_hpart(
    const float* __restrict__ am, const unsigned short* __restrict__ vst,
    float* __restrict__ ph) {
  const int tid = threadIdx.x, wave = tid >> 6, lane = tid & 63;
  const int l15 = lane & 15, quad = lane >> 4;
  const int rg = blockIdx.x, kc = blockIdx.y;
  const int row0 = rg * 64 + wave * 16;
  const int b = row0 >> 11;
  const float* arow = am + (long)(row0 + l15) * S_ + kc * 256 + quad * 8;
  const unsigned short* vb = vst + (long)b * DK_ * S_ + kc * 256 + quad * 8;
  f4 acc[4];
  for (int i = 0; i < 4; ++i) acc[i] = f4{0.f, 0.f, 0.f, 0.f};
#pragma unroll
  for (int t0 = 0; t0 < 256; t0 += 32) {
    f4 alo = *reinterpret_cast<const f4*>(arow + t0);
    f4 ahi = *reinterpret_cast<const f4*>(arow + t0 + 4);
    bf8 a = pack_bf8(alo, ahi);
#pragma unroll
    for (int i = 0; i < 4; ++i) {
      bf8 bf = ldb(vb + (long)(i * 16 + l15) * S_ + t0);
      acc[i] = MFMA(a, bf, acc[i]);
    }
  }
#pragma unroll
  for (int i = 0; i < 4; ++i)
#pragma unroll
    for (int r = 0; r < 4; ++r)
      ph[((long)kc * 4096 + row0 + quad * 4 + r) * 64 + i * 16 + l15] = acc[i][r];
}

// reduce 8 partials -> headb bf16 [row][64]
__global__ void k_hred(const float* __restrict__ ph, unsigned short* __restrict__ headb) {
  int e = blockIdx.x * 256 + threadIdx.x;      // e = row*64 + dk
  float s = 0.f;
#pragma unroll
  for (int c = 0; c < 8; ++c) s += ph[(long)c * 262144 + e];
  headb[e] = f2bf_bits(s);
}

// ---- out = head @ Wo ----
__global__ __launch_bounds__(256) void k_out(
    const unsigned short* __restrict__ head, const unsigned short* __restrict__ wot,
    float* __restrict__ out) {
  const int tid = threadIdx.x, wave = tid >> 6, lane = tid & 63;
  const int l15 = lane & 15, quad = lane >> 4;
  const int dchunk = blockIdx.x, stile = blockIdx.y, b = blockIdx.z;
  const int s0 = stile * 64 + wave * 16;
  const int n0 = dchunk * 128;
  const unsigned short* hrow = head + ((long)b * S_ + s0 + l15) * DK_ + quad * 8;
  bf8 a0 = ldb(hrow);
  bf8 a1 = ldb(hrow + 32);
  const unsigned short* wb = wot + quad * 8;
  float* obase = out + ((long)b * S_ + s0 + quad * 4) * D_ + n0 + l15;
#pragma unroll
  for (int i = 0; i < 8; ++i) {
    const unsigned short* wp = wb + (long)(n0 + i * 16 + l15) * DK_;
    bf8 b0 = ldb(wp);
    bf8 b1 = ldb(wp + 32);
    f4 d = f4{0.f, 0.f, 0.f, 0.f};
    d = MFMA(a0, b0, d);
    d = MFMA(a1, b1, d);
#pragma unroll
    for (int r = 0; r < 4; ++r) obase[(long)r * D_ + i * 16] = d[r];
  }
}

extern "C" void kernel_launch(void* const* d_in, const int* in_sizes, int n_in,
                              void* d_out, int out_size, void* d_ws, size_t ws_size,
                              hipStream_t stream) {
  const float* q  = (const float*)d_in[0];
  const float* k  = (const float*)d_in[1];
  const float* v  = (const float*)d_in[2];
  const float* Wq = (const float*)d_in[3];
  const float* Wk = (const float*)d_in[4];
  const float* Wv = (const float*)d_in[5];
  const float* Wo = (const float*)d_in[6];

  float* out = (float*)d_out;                       // [B,S,D] = 4,194,304 f32
  float* am  = out + (long)B_ * S_ * D_;            // [B,S,S] = 8,388,608 f32

  // workspace (~21.8 MB)
  unsigned short* qsb  = (unsigned short*)d_ws;     // [4096][1024]
  unsigned short* ksb  = qsb + 4194304;
  unsigned short* wqt  = ksb + 4194304;             // [1024][1024]
  unsigned short* wkt  = wqt + 1048576;
  unsigned short* wvt  = wkt + 1048576;             // [64][1024]
  unsigned short* wot  = wvt + 65536;               // [1024][64]
  unsigned short* vst  = wot + 65536;               // [B][64][S]
  unsigned short* headb= vst + 262144;              // [4096][64]
  float* recip = (float*)(headb + 262144);          // [B*H*S]

  // bf16 q,k copies live in the am region of d_out (dead before k_attn writes am)
  unsigned short* qb = (unsigned short*)am;         // [4096][1024]
  unsigned short* kb = qb + 4194304;
  // out region reuse: split-K partials [8][4096][64] f32 at [0,2M); dsum [2][65536] at [2M,2.13M)
  float* part = out;
  float* dsum = out + 2097152;

  k_prep<<<4384, 256, 0, stream>>>(q, k, Wq, Wk, Wv, Wo, qb, kb, wqt, wkt, wvt, wot);
  k_gemm_qk<<<dim3(32, 8, 2), 256, 0, stream>>>(qb, kb, wqt, wkt, qsb, ksb);
  k_pv<<<dim3(64, 8), 256, 0, stream>>>(v, wvt, part);
  k_vred<<<1024, 256, 0, stream>>>(part, vst);
  k_denom<<<dim3(32, 16, 2), 256, 0, stream>>>(qsb, ksb, dsum);
  k_recip<<<256, 256, 0, stream>>>(dsum, recip);
  k_attn<<<dim3(32, 8, 2), 512, 0, stream>>>(qsb, ksb, recip, am);
  k_hpart<<<dim3(64, 8), 256, 0, stream>>>(am, vst, part);
  k_hred<<<1024, 256, 0, stream>>>(part, headb);
  k_out<<<dim3(8, 32, 2), 256, 0, stream>>>(headb, wot, out);
}

// Round 7
// 248.607 us; speedup vs baseline: 1.0840x; 1.0840x over previous
//
#include <hip/hip_runtime.h>

// B=2, S=2048, D=1024, H=16, DK=64
// out = attn_mean @ vs @ Wo  (Wv shared across heads => mean_h(attn_h @ vs) = attn_mean @ vs)
// attn_mean[b,s,t] = (1/H) sum_h exp(score)/denom  -- no max-subtraction (scores bounded ~|2.5|)
// qs/ks layout: [b*S+s][h*64+dk]  (concatenated-head GEMM output)
// All LDS tiles are FRAGMENT-MAJOR: 16B-unit index = tile*64 + quad*16 + l15
//   -> reader addr = tilebase + lane*16B, conflict-free for ds_read_b128.
#define B_ 2
#define S_ 2048
#define D_ 1024
#define H_ 16
#define DK_ 64

typedef __bf16 bf8 __attribute__((ext_vector_type(8)));
typedef float f4 __attribute__((ext_vector_type(4)));
typedef unsigned short u16x8 __attribute__((ext_vector_type(8)));

__device__ __forceinline__ unsigned short f2bf_bits(float f) {
  unsigned int u = __float_as_uint(f);
  return (unsigned short)((u + 0x7fffu + ((u >> 16) & 1u)) >> 16);
}

__device__ __forceinline__ bf8 pack_bf8(f4 lo, f4 hi) {
  u16x8 u;
  u[0] = f2bf_bits(lo[0]); u[1] = f2bf_bits(lo[1]);
  u[2] = f2bf_bits(lo[2]); u[3] = f2bf_bits(lo[3]);
  u[4] = f2bf_bits(hi[0]); u[5] = f2bf_bits(hi[1]);
  u[6] = f2bf_bits(hi[2]); u[7] = f2bf_bits(hi[3]);
  union { u16x8 u; bf8 b; } x; x.u = u; return x.b;
}

__device__ __forceinline__ bf8 ldb(const unsigned short* p) {
  return *reinterpret_cast<const bf8*>(p);
}

__device__ __forceinline__ void stage16(const void* g, void* l) {
  __builtin_amdgcn_global_load_lds(
      (const __attribute__((address_space(1))) void*)g,
      (__attribute__((address_space(3))) void*)l, 16, 0, 0);
}

#define MFMA(a, b, c) __builtin_amdgcn_mfma_f32_16x16x32_bf16((a), (b), (c), 0, 0, 0)

// ---- merged prep: cast q,k -> bf16 rows; LDS-tiled transpose-cast weights ----
__global__ void k_prep(const float* __restrict__ q, const float* __restrict__ k,
                       const float* __restrict__ wq, const float* __restrict__ wk,
                       const float* __restrict__ wv, const float* __restrict__ wo,
                       unsigned short* __restrict__ qb, unsigned short* __restrict__ kb,
                       unsigned short* __restrict__ wqt, unsigned short* __restrict__ wkt,
                       unsigned short* __restrict__ wvt, unsigned short* __restrict__ wot) {
  __shared__ float tl[64 * 65];
  int bid = blockIdx.x, tid = threadIdx.x;
  const int rr = tid >> 6, cc = tid & 63;
  if (bid < 4096) {
    int which = bid >> 11;
    long i = ((long)(bid & 2047) * 256 + tid) * 8;
    const float* src = which ? k : q;
    unsigned short* dst = which ? kb : qb;
    f4 lo = *reinterpret_cast<const f4*>(src + i);
    f4 hi = *reinterpret_cast<const f4*>(src + i + 4);
    *reinterpret_cast<bf8*>(dst + i) = pack_bf8(lo, hi);
  } else if (bid < 4352) {
    // Wq/Wk [h][d][n=dk] -> [h][n][d], 64x64 f32 tile via LDS
    int blk = bid - 4096;
    int h = blk >> 4, d0 = (blk & 15) * 64;
    for (int m = 0; m < 2; ++m) {
      const float* src = m ? wk : wq;
      unsigned short* dst = m ? wkt : wqt;
      if (m) __syncthreads();
#pragma unroll
      for (int it = 0; it < 16; ++it) {
        int d = it * 4 + rr;
        tl[cc * 65 + d] = src[(long)h * 65536 + (d0 + d) * 64 + cc];
      }
      __syncthreads();
#pragma unroll
      for (int it = 0; it < 16; ++it) {
        int n = it * 4 + rr;
        dst[(long)h * 65536 + n * 1024 + d0 + cc] = f2bf_bits(tl[n * 65 + cc]);
      }
    }
  } else if (bid < 4368) {
    // Wv [d][n] -> [n][d]
    int d0 = (bid - 4352) * 64;
#pragma unroll
    for (int it = 0; it < 16; ++it) {
      int d = it * 4 + rr;
      tl[cc * 65 + d] = wv[(long)(d0 + d) * 64 + cc];
    }
    __syncthreads();
#pragma unroll
    for (int it = 0; it < 16; ++it) {
      int n = it * 4 + rr;
      wvt[(long)n * 1024 + d0 + cc] = f2bf_bits(tl[n * 65 + cc]);
    }
  } else {
    // Wo [kk][dd] -> [dd][kk]
    int d0 = (bid - 4368) * 64;
#pragma unroll
    for (int it = 0; it < 16; ++it) {
      int kk = it * 4 + rr;
      tl[cc * 65 + kk] = wo[(long)kk * 1024 + d0 + cc];
    }
    __syncthreads();
#pragma unroll
    for (int it = 0; it < 16; ++it) {
      int ddl = it * 4 + rr;
      wot[(long)(d0 + ddl) * 64 + cc] = f2bf_bits(tl[ddl * 65 + cc]);
    }
  }
}

// ---- GEMM: C[4096][1024] = X @ W^T, 128x128 tile, BK=64 (32 MFMA/barrier), frag-major LDS ----
// grid (32 m-tiles, 8 n-tiles, which), block 256 (4 waves 2x2; wave = 64m x 64n, 4x4 MFMA)
__global__ __launch_bounds__(256) void k_gemm_qk(
    const unsigned short* __restrict__ qb, const unsigned short* __restrict__ kb,
    const unsigned short* __restrict__ wqt, const unsigned short* __restrict__ wkt,
    unsigned short* __restrict__ qsb, unsigned short* __restrict__ ksb) {
  __shared__ unsigned short lds[16384];         // A 16 tiles @0, B 16 tiles @8192 (tile=512 shorts)
  const int tid = threadIdx.x, wave = tid >> 6, lane = tid & 63;
  const int l15 = lane & 15, quad = lane >> 4;
  const int m0 = blockIdx.x * 128, n0 = blockIdx.y * 128;
  const int which = blockIdx.z;
  const unsigned short* A = which ? kb : qb;
  const unsigned short* W = which ? wkt : wqt;
  unsigned short* C = which ? ksb : qsb;
  const float scale = which ? 1.0f : 0.18033688011112042f;  // log2(e)/8 folded into qs
  const int wr = wave >> 1, wc = wave & 1;

  f4 acc[4][4];
#pragma unroll
  for (int i = 0; i < 4; ++i)
#pragma unroll
    for (int j = 0; j < 4; ++j) acc[i][j] = f4{0.f, 0.f, 0.f, 0.f};

  for (int k0 = 0; k0 < D_; k0 += 64) {
#pragma unroll
    for (int i = 0; i < 4; ++i) {
      int u = i * 256 + tid;
      int T = u >> 6, rg = T & 7, kh = T >> 3, sl15 = u & 15, squad = (u >> 4) & 3;
      stage16(A + (long)(m0 + rg * 16 + sl15) * D_ + k0 + kh * 32 + squad * 8, lds + u * 8);
      stage16(W + (long)(n0 + rg * 16 + sl15) * D_ + k0 + kh * 32 + squad * 8,
              lds + 8192 + u * 8);
    }
    __syncthreads();
#pragma unroll
    for (int kh = 0; kh < 2; ++kh) {
      bf8 aF[4], bF[4];
#pragma unroll
      for (int mi = 0; mi < 4; ++mi)
        aF[mi] = ldb(lds + (wr * 4 + mi + 8 * kh) * 512 + lane * 8);
#pragma unroll
      for (int ni = 0; ni < 4; ++ni)
        bF[ni] = ldb(lds + 8192 + (wc * 4 + ni + 8 * kh) * 512 + lane * 8);
#pragma unroll
      for (int mi = 0; mi < 4; ++mi)
#pragma unroll
        for (int ni = 0; ni < 4; ++ni)
          acc[mi][ni] = MFMA(aF[mi], bF[ni], acc[mi][ni]);
    }
    __syncthreads();
  }
#pragma unroll
  for (int mi = 0; mi < 4; ++mi)
#pragma unroll
    for (int r = 0; r < 4; ++r) {
      long row = m0 + wr * 64 + mi * 16 + quad * 4 + r;
#pragma unroll
      for (int ni = 0; ni < 4; ++ni)
        C[row * D_ + n0 + wc * 64 + ni * 16 + l15] = f2bf_bits(acc[mi][ni][r] * scale);
    }
}

// ---- V projection split-K x8: pv[kc][row][64] f32, kc chunk = 128 ----
__global__ __launch_bounds__(256) void k_pv(
    const float* __restrict__ v, const unsigned short* __restrict__ wvt,
    float* __restrict__ pv) {
  const int tid = threadIdx.x, wave = tid >> 6, lane = tid & 63;
  const int l15 = lane & 15, quad = lane >> 4;
  const int rg = blockIdx.x, kc = blockIdx.y;
  const int row0 = rg * 64 + wave * 16;
  const float* arow = v + (long)(row0 + l15) * D_ + kc * 128 + quad * 8;
  const unsigned short* wbase = wvt + kc * 128 + quad * 8;
  f4 acc[4];
  for (int i = 0; i < 4; ++i) acc[i] = f4{0.f, 0.f, 0.f, 0.f};
#pragma unroll
  for (int k0 = 0; k0 < 128; k0 += 32) {
    f4 alo = *reinterpret_cast<const f4*>(arow + k0);
    f4 ahi = *reinterpret_cast<const f4*>(arow + k0 + 4);
    bf8 a = pack_bf8(alo, ahi);
#pragma unroll
    for (int i = 0; i < 4; ++i) {
      bf8 bf = ldb(wbase + (long)(i * 16 + l15) * D_ + k0);
      acc[i] = MFMA(a, bf, acc[i]);
    }
  }
#pragma unroll
  for (int i = 0; i < 4; ++i)
#pragma unroll
    for (int r = 0; r < 4; ++r)
      pv[((long)kc * 4096 + row0 + quad * 4 + r) * 64 + i * 16 + l15] = acc[i][r];
}

// reduce 8 k-partials -> vst[b][dk][t] bf16
__global__ void k_vred(const float* __restrict__ pv, unsigned short* __restrict__ vst) {
  int e = blockIdx.x * 256 + threadIdx.x;      // e = (b*64+dk)*2048 + t
  int t = e & 2047, dk = (e >> 11) & 63, b = e >> 17;
  long row = (long)b * S_ + t;
  float s = 0.f;
#pragma unroll
  for (int c = 0; c < 8; ++c) s += pv[((long)c * 4096 + row) * 64 + dk];
  vst[e] = f2bf_bits(s);
}

// ---- pass 1: recip[b,h,s] = 1/(H * sum_t exp2(qs.ks)) ----
// grid (16 s-tiles of 128, H, B), block 512 (8 waves x 16 s-rows)
// dbuf 2x16KB LDS, 1 barrier per t-chunk of 128; prefetch issued right after barrier
__global__ __launch_bounds__(512) void k_denom(
    const unsigned short* __restrict__ qsb, const unsigned short* __restrict__ ksb,
    float* __restrict__ recip) {
  __shared__ unsigned short lds[16384];        // 2 bufs x 8192 shorts (128t x 64dk)
  const int tid = threadIdx.x, wave = tid >> 6, lane = tid & 63;
  const int l15 = lane & 15, quad = lane >> 4;
  const int stile = blockIdx.x, h = blockIdx.y, b = blockIdx.z;
  const int s0 = stile * 128 + wave * 16;

  const unsigned short* qrow = qsb + ((long)(b * S_) + s0 + l15) * D_ + h * 64 + quad * 8;
  bf8 a0 = ldb(qrow);
  bf8 a1 = ldb(qrow + 32);

  // staging decode: u = i*512+tid (1024 16B units): rg=(u>>6)&7, kh=u>>9
  const int sl15 = tid & 15, squad = (tid >> 4) & 3;
  const unsigned short* gk[2];
#pragma unroll
  for (int i = 0; i < 2; ++i) {
    int u = i * 512 + tid;
    int rg = (u >> 6) & 7, kh = u >> 9;
    gk[i] = ksb + ((long)(b * S_) + rg * 16 + sl15) * D_ + h * 64 + kh * 32 + squad * 8;
  }
#pragma unroll
  for (int i = 0; i < 2; ++i) stage16(gk[i], lds + (i * 512 + tid) * 8);

  f4 sum = f4{0.f, 0.f, 0.f, 0.f};
  for (int it = 0; it < 16; ++it) {
    __syncthreads();
    if (it < 15) {
      int bufn = (it + 1) & 1;
#pragma unroll
      for (int i = 0; i < 2; ++i)
        stage16(gk[i] + (long)(it + 1) * 128 * D_, lds + bufn * 8192 + (i * 512 + tid) * 8);
    }
    const unsigned short* L = lds + (it & 1) * 8192;
#pragma unroll
    for (int tt = 0; tt < 8; ++tt) {
      bf8 b0 = ldb(L + tt * 512 + lane * 8);
      bf8 b1 = ldb(L + 4096 + tt * 512 + lane * 8);
      f4 d = f4{0.f, 0.f, 0.f, 0.f};
      d = MFMA(a0, b0, d);
      d = MFMA(a1, b1, d);
#pragma unroll
      for (int r = 0; r < 4; ++r) sum[r] += __builtin_amdgcn_exp2f(d[r]);
    }
  }
#pragma unroll
  for (int m = 1; m < 16; m <<= 1) {
#pragma unroll
    for (int r = 0; r < 4; ++r) sum[r] += __shfl_xor(sum[r], m, 64);
  }
  if (l15 == 0) {
    float* rp = recip + (long)(b * H_ + h) * S_ + s0 + quad * 4;
#pragma unroll
    for (int r = 0; r < 4; ++r) rp[r] = 1.0f / (16.0f * sum[r]);
  }
}

// ---- pass 2: attn_mean[b,s,t] = sum_h recip[b,h,s]*exp2(score) ----
// grid (16 t-chunks of 128, 16 s-tiles of 128, B), block 512 (8 waves x 16 s-rows)
// dbuf 2x16KB LDS, 1 barrier per head; ks prefetch after barrier; q-frags + recip
// for head h+1 register-prefetched during head h's compute
__global__ __launch_bounds__(512) void k_attn(
    const unsigned short* __restrict__ qsb, const unsigned short* __restrict__ ksb,
    const float* __restrict__ recip, float* __restrict__ am) {
  __shared__ unsigned short lds[16384];        // 2 bufs x 8192 shorts (128t x 64dk)
  const int tid = threadIdx.x, wave = tid >> 6, lane = tid & 63;
  const int l15 = lane & 15, quad = lane >> 4;
  const int tchunk = blockIdx.x, stile = blockIdx.y, b = blockIdx.z;
  const int s0 = stile * 128 + wave * 16;
  const int t0c = tchunk * 128;

  f4 acc[8];
#pragma unroll
  for (int tt = 0; tt < 8; ++tt) acc[tt] = f4{0.f, 0.f, 0.f, 0.f};

  const unsigned short* qrow = qsb + ((long)(b * S_) + s0 + l15) * D_ + quad * 8;
  const float* rbase = recip + (long)b * H_ * S_ + s0 + quad * 4;

  // staging decode: u = i*512+tid (1024 16B units): rg=(u>>6)&7, kh=u>>9
  const int sl15 = tid & 15, squad = (tid >> 4) & 3;
  const unsigned short* gk[2];
#pragma unroll
  for (int i = 0; i < 2; ++i) {
    int u = i * 512 + tid;
    int rg = (u >> 6) & 7, kh = u >> 9;
    gk[i] = ksb + ((long)(b * S_) + t0c + rg * 16 + sl15) * D_ + kh * 32 + squad * 8;
  }
#pragma unroll
  for (int i = 0; i < 2; ++i) stage16(gk[i], lds + (i * 512 + tid) * 8);

  bf8 a0 = ldb(qrow);
  bf8 a1 = ldb(qrow + 32);
  f4 rp = *reinterpret_cast<const f4*>(rbase);

  for (int h = 0; h < H_; ++h) {
    __syncthreads();
    if (h < 15) {
      int bufn = (h + 1) & 1;
#pragma unroll
      for (int i = 0; i < 2; ++i)
        stage16(gk[i] + (h + 1) * 64, lds + bufn * 8192 + (i * 512 + tid) * 8);
    }
    bf8 a0c = a0, a1c = a1;
    f4 rpc = rp;
    if (h < 15) {                               // register-prefetch next head
      a0 = ldb(qrow + (h + 1) * 64);
      a1 = ldb(qrow + (h + 1) * 64 + 32);
      rp = *reinterpret_cast<const f4*>(rbase + (long)(h + 1) * S_);
    }
    const unsigned short* L = lds + (h & 1) * 8192;
#pragma unroll
    for (int tt = 0; tt < 8; ++tt) {
      bf8 b0 = ldb(L + tt * 512 + lane * 8);
      bf8 b1 = ldb(L + 4096 + tt * 512 + lane * 8);
      f4 d = f4{0.f, 0.f, 0.f, 0.f};
      d = MFMA(a0c, b0, d);
      d = MFMA(a1c, b1, d);
#pragma unroll
      for (int r = 0; r < 4; ++r) acc[tt][r] += rpc[r] * __builtin_amdgcn_exp2f(d[r]);
    }
  }
  float* obase = am + ((long)b * S_ + s0 + quad * 4) * S_ + t0c + l15;
#pragma unroll
  for (int tt = 0; tt < 8; ++tt)
#pragma unroll
    for (int r = 0; r < 4; ++r) obase[(long)r * S_ + tt * 16] = acc[tt][r];
}

// ---- head split-K x8: ph[kc][row][64] f32 = am-chunk @ vs-chunk, kc chunk = 256 t ----
__global__ __launch_bounds__(256) void k_hpart(
    const float* __restrict__ am, const unsigned short* __restrict__ vst,
    float* __restrict__ ph) {
  const int tid = threadIdx.x, wave = tid >> 6, lane = tid & 63;
  const int l15 = lane & 15, quad = lane >> 4;
  const int rg = blockIdx.x, kc = blockIdx.y;
  const int row0 = rg * 64 + wave * 16;
  const int b = row0 >> 11;
  const float* arow = am + (long)(row0 + l15) * S_ + kc * 256 + quad * 8;
  const unsigned short* vb = vst + (long)b * DK_ * S_ + kc * 256 + quad * 8;
  f4 acc[4];
  for (int i = 0; i < 4; ++i) acc[i] = f4{0.f, 0.f, 0.f, 0.f};
#pragma unroll
  for (int t0 = 0; t0 < 256; t0 += 32) {
    f4 alo = *reinterpret_cast<const f4*>(arow + t0);
    f4 ahi = *reinterpret_cast<const f4*>(arow + t0 + 4);
    bf8 a = pack_bf8(alo, ahi);
#pragma unroll
    for (int i = 0; i < 4; ++i) {
      bf8 bf = ldb(vb + (long)(i * 16 + l15) * S_ + t0);
      acc[i] = MFMA(a, bf, acc[i]);
    }
  }
#pragma unroll
  for (int i = 0; i < 4; ++i)
#pragma unroll
    for (int r = 0; r < 4; ++r)
      ph[((long)kc * 4096 + row0 + quad * 4 + r) * 64 + i * 16 + l15] = acc[i][r];
}

// reduce 8 partials -> headb bf16 [row][64]
__global__ void k_hred(const float* __restrict__ ph, unsigned short* __restrict__ headb) {
  int e = blockIdx.x * 256 + threadIdx.x;      // e = row*64 + dk
  float s = 0.f;
#pragma unroll
  for (int c = 0; c < 8; ++c) s += ph[(long)c * 262144 + e];
  headb[e] = f2bf_bits(s);
}

// ---- out = head @ Wo ----
__global__ __launch_bounds__(256) void k_out(
    const unsigned short* __restrict__ head, const unsigned short* __restrict__ wot,
    float* __restrict__ out) {
  const int tid = threadIdx.x, wave = tid >> 6, lane = tid & 63;
  const int l15 = lane & 15, quad = lane >> 4;
  const int dchunk = blockIdx.x, stile = blockIdx.y, b = blockIdx.z;
  const int s0 = stile * 64 + wave * 16;
  const int n0 = dchunk * 128;
  const unsigned short* hrow = head + ((long)b * S_ + s0 + l15) * DK_ + quad * 8;
  bf8 a0 = ldb(hrow);
  bf8 a1 = ldb(hrow + 32);
  const unsigned short* wb = wot + quad * 8;
  float* obase = out + ((long)b * S_ + s0 + quad * 4) * D_ + n0 + l15;
#pragma unroll
  for (int i = 0; i < 8; ++i) {
    const unsigned short* wp = wb + (long)(n0 + i * 16 + l15) * DK_;
    bf8 b0 = ldb(wp);
    bf8 b1 = ldb(wp + 32);
    f4 d = f4{0.f, 0.f, 0.f, 0.f};
    d = MFMA(a0, b0, d);
    d = MFMA(a1, b1, d);
#pragma unroll
    for (int r = 0; r < 4; ++r) obase[(long)r * D_ + i * 16] = d[r];
  }
}

extern "C" void kernel_launch(void* const* d_in, const int* in_sizes, int n_in,
                              void* d_out, int out_size, void* d_ws, size_t ws_size,
                              hipStream_t stream) {
  const float* q  = (const float*)d_in[0];
  const float* k  = (const float*)d_in[1];
  const float* v  = (const float*)d_in[2];
  const float* Wq = (const float*)d_in[3];
  const float* Wk = (const float*)d_in[4];
  const float* Wv = (const float*)d_in[5];
  const float* Wo = (const float*)d_in[6];

  float* out = (float*)d_out;                       // [B,S,D] = 4,194,304 f32
  float* am  = out + (long)B_ * S_ * D_;            // [B,S,S] = 8,388,608 f32

  // workspace (~21.8 MB)
  unsigned short* qsb  = (unsigned short*)d_ws;     // [4096][1024]
  unsigned short* ksb  = qsb + 4194304;
  unsigned short* wqt  = ksb + 4194304;             // [1024][1024]
  unsigned short* wkt  = wqt + 1048576;
  unsigned short* wvt  = wkt + 1048576;             // [64][1024]
  unsigned short* wot  = wvt + 65536;               // [1024][64]
  unsigned short* vst  = wot + 65536;               // [B][64][S]
  unsigned short* headb= vst + 262144;              // [4096][64]
  float* recip = (float*)(headb + 262144);          // [B*H*S]

  // bf16 q,k copies live in the am region of d_out (dead before k_attn writes am)
  unsigned short* qb = (unsigned short*)am;         // [4096][1024]
  unsigned short* kb = qb + 4194304;
  // split-K f32 partials [8][4096][64] = 8 MB live in the out region (dead until k_out)
  float* part = out;

  k_prep<<<4384, 256, 0, stream>>>(q, k, Wq, Wk, Wv, Wo, qb, kb, wqt, wkt, wvt, wot);
  k_gemm_qk<<<dim3(32, 8, 2), 256, 0, stream>>>(qb, kb, wqt, wkt, qsb, ksb);
  k_pv<<<dim3(64, 8), 256, 0, stream>>>(v, wvt, part);
  k_vred<<<1024, 256, 0, stream>>>(part, vst);
  k_denom<<<dim3(16, 16, 2), 512, 0, stream>>>(qsb, ksb, recip);
  k_attn<<<dim3(16, 16, 2), 512, 0, stream>>>(qsb, ksb, recip, am);
  k_hpart<<<dim3(64, 8), 256, 0, stream>>>(am, vst, part);
  k_hred<<<1024, 256, 0, stream>>>(part, headb);
  k_out<<<dim3(8, 32, 2), 256, 0, stream>>>(headb, wot, out);
}